// Round 13
// baseline (142.939 us; speedup 1.0000x reference)
//
#include <hip/hip_runtime.h>
#include <hip/hip_bf16.h>
#include <stdint.h>
#include <type_traits>

// ---------------------------------------------------------------------------
// Fused attention: out = softmax((x Wq^T)(x Wk^T)^T / sqrt(d)) (x Wv^T)
// B=4, S=2048, D=1024, fp32 in/out, bf16 MFMA internal compute.
//
// R13: proj moved to the BM=256/BN=256 geometry (wave tile 128x64 — lowest
// LDS-read:MFMA ratio) as ONE fused-N GEMM: x[8192x1024] @ Wcat[3072x1024]^T
// (Wq,Wk,Wv contiguous = [3072][1024]). nbm=32 x nbn=12 = 384 blocks.
// Epilogue M_PROJ3 splits by column segment: Q / K / V-transposed.
// Scores/PV/cast unchanged from R12 (2-phase K-tile, counted vmcnt, T2
// swizzle, exp+rowsum fused in scores, 1/rowsum in PV).
// ---------------------------------------------------------------------------

typedef __attribute__((ext_vector_type(8))) short short8;
typedef __attribute__((ext_vector_type(4))) float f32x4;

#define GL_G(p) ((const __attribute__((address_space(1))) void*)(p))
#define GL_L(p) ((__attribute__((address_space(3))) void*)(p))

__device__ __forceinline__ float bf2f(unsigned short u) {
  union { float f; uint32_t i; } c; c.i = ((uint32_t)u) << 16; return c.f;
}
__device__ __forceinline__ unsigned short f2bf(float f) {
  __hip_bfloat16 h = __float2bfloat16(f);
  return *reinterpret_cast<unsigned short*>(&h);
}

// ---- fused cast: x (XE elems) then Wq,Wk,Wv (WE each) -> bf16, exact grid --
__global__ __launch_bounds__(256) void cast_all(
    const float* __restrict__ x, const float* __restrict__ wq,
    const float* __restrict__ wk, const float* __restrict__ wv,
    unsigned short* __restrict__ xb, unsigned short* __restrict__ wb) {
  const long XE = 4L * 2048 * 1024;
  const long WE = 1L << 20;
  long j = ((long)blockIdx.x * blockDim.x + threadIdx.x) * 8;
  const float* src;
  unsigned short* dst;
  long loc;
  if (j < XE) {
    src = x; dst = xb; loc = j;
  } else {
    long jw = j - XE;
    int sel = (int)(jw >> 20);
    src = (sel == 0) ? wq : (sel == 1) ? wk : wv;
    dst = wb + (long)sel * WE;
    loc = jw & (WE - 1);
  }
  float4 a = *(const float4*)(src + loc);
  float4 b = *(const float4*)(src + loc + 4);
  uint4 pk;
  pk.x = (uint32_t)f2bf(a.x) | ((uint32_t)f2bf(a.y) << 16);
  pk.y = (uint32_t)f2bf(a.z) | ((uint32_t)f2bf(a.w) << 16);
  pk.z = (uint32_t)f2bf(b.x) | ((uint32_t)f2bf(b.y) << 16);
  pk.w = (uint32_t)f2bf(b.z) | ((uint32_t)f2bf(b.w) << 16);
  *(uint4*)(dst + ((j < XE) ? j : loc)) = pk;
}

template <int N>
__device__ __forceinline__ void waitv() {
  asm volatile("s_waitcnt vmcnt(%0)" :: "n"(N) : "memory");
}
__device__ __forceinline__ void barrier_() {
  asm volatile("" ::: "memory");
  __builtin_amdgcn_s_barrier();
  asm volatile("" ::: "memory");
}

// modes
#define M_PROJ3 0
#define M_SCORES 1
#define M_PV 2

// ---------------- NT GEMM device body, BMxBN tile, BK=64, 2-phase ---------
// C[m,n] = scale-op( sum_k A[m,k] B[n,k] ). All shape params compile-time.
// Grid 1D = nbm*nbn*nz, %8==0. 8 waves (2M x 4N); wave tile (BM/2)x(BN/4).
template <int BM, int BN, int MODE, int K, int LDA, int LDB, int LDC,
          typename OUT_T>
__device__ __forceinline__ void gemm_body(
    const unsigned short* __restrict__ A, const unsigned short* __restrict__ B,
    OUT_T* __restrict__ C, long sA, long sB, long sC, float scale, int nbm,
    int nbn, char* smem, float* __restrict__ rs) {
  constexpr int BK = 64;
  constexpr int WVN = BN / 4;    // per-wave N: 64
  constexpr int NREP = WVN / 16; // 4
  constexpr int NPH = NREP / 2;  // frags per B-half: 2
  constexpr int AF = BM / 64;    // A-frags per half per wave: 4 or 2
  constexpr int AHALF = (BM / 2) * BK * 2; // 16384 or 8192 B
  constexpr int BHALF = (BN / 2) * BK * 2; // 16384 B
  constexpr int LA = AHALF / 8192;         // gloads per A-half: 2 or 1
  constexpr int LB = BHALF / 8192;         // gloads per B-half: 2
  constexpr int TL = 2 * (LA + LB);        // loads per K-tile: 8 or 6
  constexpr int WAITN = LA + 2 * LB;       // steady vmcnt at end-PH1
  constexpr int STG = 4 * AHALF + 4 * BHALF;
  constexpr int NT = K / BK;               // K-tiles (even)
  static_assert((NT & 1) == 0 && NT >= 4, "even NT >= 4");

  const int tid = threadIdx.x;
  const int wid = tid >> 6, lane = tid & 63;
  const int wm = wid >> 2, wn = wid & 3;
  const int fr = lane & 15;
  const int kq = lane >> 4;  // 0..3

  // XCD-aware bijective swizzle (gridDim %8==0), n-major decode.
  const int NB = gridDim.x;
  const int p = blockIdx.x;
  const int l = (p & 7) * (NB >> 3) + (p >> 3);
  const int pb = nbm * nbn;
  const int z = l / pb;
  const int mn = l - z * pb;
  const int bm = mn / nbn, bn = mn - bm * nbn;
  const unsigned short* Az = A + (long)z * sA;
  const unsigned short* Bz = B + (long)z * sB;
  const long brow = (long)bm * BM, bcol = (long)bn * BN;

  // PV: build inv[BM] from rs before the K-loop (region smem+STG).
  float* invp = (float*)(smem + STG);
  if constexpr (MODE == M_PV) {
    if (tid < BM) {
      const float* r8 = rs + ((long)z * 2048 + brow + tid) * 8;
      float s = ((r8[0] + r8[1]) + (r8[2] + r8[3])) +
                ((r8[4] + r8[5]) + (r8[6] + r8[7]));
      invp[tid] = 1.0f / s;
    }
  }

  // staging: each load = 512 thr x 16B = 64 rows x 128B. source col is
  // pre-swizzled so linear LDS write == swizzled layout (m173/m201 pattern).
  const int srow = tid >> 3;  // 0..63
  const int scolb = ((tid & 7) * 16) ^ ((srow & 7) << 4);

  auto stageA = [&](int buf, int half, int kt) {
#pragma unroll
    for (int part = 0; part < LA; ++part) {
      const char* g = (const char*)Az +
          ((brow + half * (BM / 2) + part * 64 + srow) * (long)LDA + kt) * 2 +
          scolb;
      __builtin_amdgcn_global_load_lds(
          GL_G(g),
          GL_L(smem + (buf * 2 + half) * AHALF + part * 8192 + wid * 1024),
          16, 0, 0);
    }
  };
  auto stageB = [&](int buf, int half, int kt) {
#pragma unroll
    for (int part = 0; part < LB; ++part) {
      const char* g = (const char*)Bz +
          ((bcol + half * (BN / 2) + part * 64 + srow) * (long)LDB + kt) * 2 +
          scolb;
      __builtin_amdgcn_global_load_lds(
          GL_G(g),
          GL_L(smem + 4 * AHALF + (buf * 2 + half) * BHALF + part * 8192 +
               wid * 1024),
          16, 0, 0);
    }
  };

  f32x4 acc[2 * AF][NREP];
#pragma unroll
  for (int m = 0; m < 2 * AF; ++m)
#pragma unroll
    for (int n = 0; n < NREP; ++n) acc[m][n] = (f32x4){0.f, 0.f, 0.f, 0.f};

  short8 af[AF][2];   // current A-half (reloaded each phase)
  short8 b0[NPH][2];  // B-half 0 (read PH0, reused PH1)
  short8 b1[NPH][2];  // B-half 1 (read PH0, reused PH1)

  // per-lane invariant pieces of the ds_read addresses
  const int aRow = wm * (BM / 4) + fr;          // + i*16
  const int bRow = wn * (WVN / 2) + fr;         // + j*16
  const int swz = (fr & 7) << 4;

  auto readA = [&](auto curC, int mh) {
    constexpr int cur = decltype(curC)::value;
#pragma unroll
    for (int i = 0; i < AF; ++i)
#pragma unroll
      for (int ks = 0; ks < 2; ++ks) {
        const int off = (cur * 2 + mh) * AHALF + (aRow + i * 16) * 128 +
                        ((ks * 64 + kq * 16) ^ swz);
        af[i][ks] = *(const short8*)(smem + off);
      }
  };
  auto readB = [&](short8 (&bf_)[NPH][2], auto curC, int nh) {
    constexpr int cur = decltype(curC)::value;
#pragma unroll
    for (int j = 0; j < NPH; ++j)
#pragma unroll
      for (int ks = 0; ks < 2; ++ks) {
        const int off = 4 * AHALF + (cur * 2 + nh) * BHALF +
                        (bRow + j * 16) * 128 + ((ks * 64 + kq * 16) ^ swz);
        bf_[j][ks] = *(const short8*)(smem + off);
      }
  };
  auto mfma2 = [&](int mh) {  // A-half mh x {B0, B1}
    __builtin_amdgcn_s_setprio(1);
#pragma unroll
    for (int i = 0; i < AF; ++i)
#pragma unroll
      for (int nh = 0; nh < 2; ++nh)
#pragma unroll
        for (int j = 0; j < NPH; ++j)
#pragma unroll
          for (int ks = 0; ks < 2; ++ks) {
            short8(&bb)[NPH][2] = nh ? b1 : b0;
            acc[mh * AF + i][nh * NPH + j] =
                __builtin_amdgcn_mfma_f32_16x16x32_bf16(
                    af[i][ks], bb[j][ks], acc[mh * AF + i][nh * NPH + j], 0, 0,
                    0);
          }
    __builtin_amdgcn_s_setprio(0);
  };

  // one K-tile body; CUR compile-time.
  auto tile = [&](auto curC, int t) {
    constexpr int cur = decltype(curC)::value;
    constexpr int nxt = cur ^ 1;
    const int kt1 = (t + 1) * BK;
    const int kt2 = (t + 2) * BK;
    const bool more2 = (t + 2) < NT;

    // ---- PH0: read A0,B0,B1; stage A1(t+1)[t>=1]; MFMA A0x{B0,B1} ----
    readA(std::integral_constant<int, cur>{}, 0);
    readB(b0, std::integral_constant<int, cur>{}, 0);
    readB(b1, std::integral_constant<int, cur>{}, 1);
    if (t >= 1 && t + 1 < NT) stageA(nxt, 1, kt1);
    mfma2(0);
    barrier_();

    // ---- PH1: read A1; stage A0,B0,B1(t+2); MFMA A1x{B0,B1}; wait ----
    readA(std::integral_constant<int, cur>{}, 1);
    if (more2) { stageA(cur, 0, kt2); stageB(cur, 0, kt2); stageB(cur, 1, kt2); }
    mfma2(1);
    if (more2) waitv<WAITN>(); else waitv<0>();
    barrier_();
  };

  // prologue: tiles 0 and 1 fully staged; drain tile 0 only.
  stageA(0, 0, 0); stageB(0, 0, 0); stageB(0, 1, 0); stageA(0, 1, 0);
  stageA(1, 0, BK); stageB(1, 0, BK); stageB(1, 1, BK); stageA(1, 1, BK);
  waitv<TL>();
  barrier_();

#pragma unroll 1
  for (int tt = 0; tt < NT; tt += 2) {
    tile(std::integral_constant<int, 0>{}, tt);
    tile(std::integral_constant<int, 1>{}, tt + 1);
  }

  // ---- epilogue: C/D layout col = lane&15, row = (lane>>4)*4 + r ----
  float rp[2 * AF][4];
  if constexpr (MODE == M_SCORES) {
#pragma unroll
    for (int m = 0; m < 2 * AF; ++m)
#pragma unroll
      for (int r = 0; r < 4; ++r) rp[m][r] = 0.f;
  }

#pragma unroll
  for (int m = 0; m < 2 * AF; ++m) {
    const int mh = m / AF, i = m % AF;
    const long rowg0 = brow + mh * (BM / 2) + wm * (BM / 4) + i * 16 + kq * 4;
    const int lrow0 = mh * (BM / 2) + wm * (BM / 4) + i * 16 + kq * 4;
#pragma unroll
    for (int n = 0; n < NREP; ++n) {
      const int nh = n / NPH, j = n % NPH;
      const long colg = bcol + nh * (BN / 2) + wn * (WVN / 2) + j * 16 + fr;
      f32x4 v = acc[m][n];
      if constexpr (MODE == M_SCORES) {
        unsigned short* Cz = (unsigned short*)C + z * sC;
#pragma unroll
        for (int r = 0; r < 4; ++r) {
          float e = __expf(v[r] * scale);
          Cz[(rowg0 + r) * LDC + colg] = f2bf(e);
          rp[m][r] += e;
        }
      } else if constexpr (MODE == M_PV) {
        float* Cz = (float*)C + z * sC;
#pragma unroll
        for (int r = 0; r < 4; ++r)
          Cz[(rowg0 + r) * LDC + colg] = v[r] * invp[lrow0 + r];
      } else {  // M_PROJ3: fused QKV, split by column segment.
        unsigned short* Cq = (unsigned short*)C;  // Qb; Kb at +XE; Vtb at +2XE
        constexpr long XE = 4L * 2048 * 1024;
        if (colg < 2048) {
          unsigned short* dst = Cq + (colg >> 10) * XE;
#pragma unroll
          for (int r = 0; r < 4; ++r)
            dst[(rowg0 + r) * 1024 + (colg & 1023)] = f2bf(v[r]);
        } else {
          // transposed store: Vt[b][e][s], b = row>>11, s = row&2047
          const long e = colg - 2048;
          const long bb = rowg0 >> 11;
          ushort4 pk;
          pk.x = f2bf(v[0]); pk.y = f2bf(v[1]);
          pk.z = f2bf(v[2]); pk.w = f2bf(v[3]);
          *(ushort4*)(Cq + 2 * XE + bb * (1024L * 2048) + e * 2048 +
                      (rowg0 & 2047)) = pk;
        }
      }
    }
  }

  if constexpr (MODE == M_SCORES) {
    // reduce rp over fr lanes, across the 4 wn waves via LDS, one store/row.
#pragma unroll
    for (int m = 0; m < 2 * AF; ++m)
#pragma unroll
      for (int r = 0; r < 4; ++r) {
        float tv = rp[m][r];
        tv += __shfl_xor(tv, 1);
        tv += __shfl_xor(tv, 2);
        tv += __shfl_xor(tv, 4);
        tv += __shfl_xor(tv, 8);
        rp[m][r] = tv;
      }
    float* part = (float*)smem;  // [BM][4] — staging region is dead now
    if (fr == 0) {
#pragma unroll
      for (int m = 0; m < 2 * AF; ++m) {
        const int mh = m / AF, i = m % AF;
#pragma unroll
        for (int r = 0; r < 4; ++r) {
          const int lrow = mh * (BM / 2) + wm * (BM / 4) + i * 16 + kq * 4 + r;
          part[lrow * 4 + wn] = rp[m][r];
        }
      }
    }
    __syncthreads();
    if (tid < BM) {
      float s = (part[tid * 4 + 0] + part[tid * 4 + 1]) +
                (part[tid * 4 + 2] + part[tid * 4 + 3]);
      rs[((long)z * 2048 + brow + tid) * 8 + bn] = s;
    }
  }
}

// named kernel wrappers
__global__ __launch_bounds__(512, 2) void gemm_proj(
    const unsigned short* __restrict__ A, const unsigned short* __restrict__ B,
    unsigned short* __restrict__ C, long sA, long sB, long sC, float scale,
    int nbm, int nbn) {
  __shared__ __align__(16) char smem[131072];
  gemm_body<256, 256, M_PROJ3, 1024, 1024, 1024, 1024, unsigned short>(
      A, B, C, sA, sB, sC, scale, nbm, nbn, smem, nullptr);
}
__global__ __launch_bounds__(512, 2) void gemm_scores(
    const unsigned short* __restrict__ A, const unsigned short* __restrict__ B,
    unsigned short* __restrict__ C, long sA, long sB, long sC, float scale,
    int nbm, int nbn, float* rs) {
  __shared__ __align__(16) char smem[131072];
  gemm_body<256, 256, M_SCORES, 1024, 1024, 1024, 2048, unsigned short>(
      A, B, C, sA, sB, sC, scale, nbm, nbn, smem, rs);
}
__global__ __launch_bounds__(512, 2) void gemm_pv(
    const unsigned short* __restrict__ A, const unsigned short* __restrict__ B,
    float* __restrict__ C, long sA, long sB, long sC, float scale,
    int nbm, int nbn, float* rs) {
  __shared__ __align__(16) char smem[98304 + 512];
  gemm_body<128, 256, M_PV, 2048, 2048, 2048, 1024, float>(
      A, B, C, sA, sB, sC, scale, nbm, nbn, smem, rs);
}

// ---------------------------------------------------------------------------
extern "C" void kernel_launch(void* const* d_in, const int* in_sizes, int n_in,
                              void* d_out, int out_size, void* d_ws,
                              size_t ws_size, hipStream_t stream) {
  const float* x = (const float*)d_in[0];
  const float* Wq = (const float*)d_in[1];
  const float* Wk = (const float*)d_in[2];
  const float* Wv = (const float*)d_in[3];
  float* out = (float*)d_out;

  const long XE = 4L * 2048 * 1024;  // 8,388,608 elems
  const long WE = 1024L * 1024;      // 1,048,576 elems
  const long SE = 4L * 2048 * 2048;  // 16,777,216 elems

  unsigned short* xb = (unsigned short*)d_ws;
  unsigned short* Wqb = xb + XE;     // Wq,Wk,Wv contiguous = Wcat[3072][1024]
  unsigned short* Qb = Wqb + 3 * WE; // Qb,Kb,Vtb contiguous
  unsigned short* Vtb = Qb + 2 * XE; // [b][e][s] (transposed V)
  unsigned short* Sb = Vtb + XE;     // [b][q][k] p~ = exp(s/32), bf16
  unsigned short* Kb = Qb + XE;
  float* rs = (float*)(Sb + SE);     // [4*2048 rows][8 colblocks] partials
  if (ws_size < (size_t)(4 * XE + 3 * WE + SE) * 2 + 8192 * 8 * 4) return;

  // fused casts: (XE + 3*WE)/8 threads = 1,441,792 -> 5632 blocks exact
  cast_all<<<5632, 256, 0, stream>>>(x, Wq, Wk, Wv, xb, Wqb);

  // fused QKV projection: [8192 x 3072] = x @ Wcat^T, BM=256/BN=256,
  // nbm=32 x nbn=12 = 384 blocks. Epilogue splits Q / K / Vt(transposed).
  gemm_proj<<<384, 512, 0, stream>>>(xb, Wqb, Qb, 0, 0, 0, 1.0f, 32, 12);
  // p~[b][q][k] = exp(Qb Kb^T / 32), per batch + row partial sums.
  gemm_scores<<<256, 512, 0, stream>>>(Qb, Kb, Sb, 2048L * 1024, 2048L * 1024,
                                       2048L * 2048, 0.03125f, 8, 8, rs);
  // out[b][q][e] = (p~ Vt^T) / rowsum: BM=128 -> 16*4*4 = 256 blocks, 1 round
  gemm_pv<<<256, 512, 0, stream>>>(Sb, Vtb, out, 2048L * 2048, 1024L * 2048,
                                   2048L * 1024, 1.0f, 16, 4, rs);
}

// Round 14
// 137.903 us; speedup vs baseline: 1.0365x; 1.0365x over previous
//
#include <hip/hip_runtime.h>
#include <hip/hip_bf16.h>
#include <stdint.h>
#include <type_traits>

// ---------------------------------------------------------------------------
// Fused attention: out = softmax((x Wq^T)(x Wk^T)^T / sqrt(d)) (x Wv^T)
// B=4, S=2048, D=1024, fp32 in/out, bf16 MFMA internal compute.
//
// R14: occupancy play. proj + PV move to BM=BN=128 (LDS 64KB -> 2 blocks/CU,
// launch_bounds(512,4)); cross-block overlap covers barrier/stage stalls
// (m97/m114 mechanism). proj = fused-N single GEMM [8192x3072] with
// M_PROJ3 split epilogue, 64x24x1 = 1536 blocks = 3 full rounds at 2/CU.
// PV: 16x8x4 = 512 blocks = 1 full round at 2/CU. scores unchanged
// (256x256, 256 blocks). Engine schedule identical to R12/R13.
// ---------------------------------------------------------------------------

typedef __attribute__((ext_vector_type(8))) short short8;
typedef __attribute__((ext_vector_type(4))) float f32x4;

#define GL_G(p) ((const __attribute__((address_space(1))) void*)(p))
#define GL_L(p) ((__attribute__((address_space(3))) void*)(p))

__device__ __forceinline__ float bf2f(unsigned short u) {
  union { float f; uint32_t i; } c; c.i = ((uint32_t)u) << 16; return c.f;
}
__device__ __forceinline__ unsigned short f2bf(float f) {
  __hip_bfloat16 h = __float2bfloat16(f);
  return *reinterpret_cast<unsigned short*>(&h);
}

// ---- fused cast: x (XE elems) then Wq,Wk,Wv (WE each) -> bf16, exact grid --
__global__ __launch_bounds__(256) void cast_all(
    const float* __restrict__ x, const float* __restrict__ wq,
    const float* __restrict__ wk, const float* __restrict__ wv,
    unsigned short* __restrict__ xb, unsigned short* __restrict__ wb) {
  const long XE = 4L * 2048 * 1024;
  const long WE = 1L << 20;
  long j = ((long)blockIdx.x * blockDim.x + threadIdx.x) * 8;
  const float* src;
  unsigned short* dst;
  long loc;
  if (j < XE) {
    src = x; dst = xb; loc = j;
  } else {
    long jw = j - XE;
    int sel = (int)(jw >> 20);
    src = (sel == 0) ? wq : (sel == 1) ? wk : wv;
    dst = wb + (long)sel * WE;
    loc = jw & (WE - 1);
  }
  float4 a = *(const float4*)(src + loc);
  float4 b = *(const float4*)(src + loc + 4);
  uint4 pk;
  pk.x = (uint32_t)f2bf(a.x) | ((uint32_t)f2bf(a.y) << 16);
  pk.y = (uint32_t)f2bf(a.z) | ((uint32_t)f2bf(a.w) << 16);
  pk.z = (uint32_t)f2bf(b.x) | ((uint32_t)f2bf(b.y) << 16);
  pk.w = (uint32_t)f2bf(b.z) | ((uint32_t)f2bf(b.w) << 16);
  *(uint4*)(dst + ((j < XE) ? j : loc)) = pk;
}

template <int N>
__device__ __forceinline__ void waitv() {
  asm volatile("s_waitcnt vmcnt(%0)" :: "n"(N) : "memory");
}
__device__ __forceinline__ void barrier_() {
  asm volatile("" ::: "memory");
  __builtin_amdgcn_s_barrier();
  asm volatile("" ::: "memory");
}

// modes
#define M_PROJ3 0
#define M_SCORES 1
#define M_PV 2

// ---------------- NT GEMM device body, BMxBN tile, BK=64, 2-phase ---------
// C[m,n] = scale-op( sum_k A[m,k] B[n,k] ). All shape params compile-time.
// Grid 1D = nbm*nbn*nz, %8==0. 8 waves (2M x 4N); wave tile (BM/2)x(BN/4).
template <int BM, int BN, int MODE, int K, int LDA, int LDB, int LDC,
          typename OUT_T>
__device__ __forceinline__ void gemm_body(
    const unsigned short* __restrict__ A, const unsigned short* __restrict__ B,
    OUT_T* __restrict__ C, long sA, long sB, long sC, float scale, int nbm,
    int nbn, char* smem, float* __restrict__ rs) {
  constexpr int BK = 64;
  constexpr int WVN = BN / 4;    // per-wave N: 64 or 32
  constexpr int NREP = WVN / 16; // 4 or 2
  constexpr int NPH = NREP / 2;  // frags per B-half: 2 or 1
  constexpr int AF = BM / 64;    // A-frags per half per wave: 4 or 2
  constexpr int AHALF = (BM / 2) * BK * 2; // 16384 or 8192 B
  constexpr int BHALF = (BN / 2) * BK * 2; // 16384 or 8192 B
  constexpr int LA = AHALF / 8192;         // gloads per A-half
  constexpr int LB = BHALF / 8192;         // gloads per B-half
  constexpr int TL = 2 * (LA + LB);        // loads per K-tile
  constexpr int WAITN = LA + 2 * LB;       // steady vmcnt at end-PH1
  constexpr int STG = 4 * AHALF + 4 * BHALF;
  constexpr int NT = K / BK;               // K-tiles (even)
  static_assert((NT & 1) == 0 && NT >= 4, "even NT >= 4");

  const int tid = threadIdx.x;
  const int wid = tid >> 6, lane = tid & 63;
  const int wm = wid >> 2, wn = wid & 3;
  const int fr = lane & 15;
  const int kq = lane >> 4;  // 0..3

  // XCD-aware bijective swizzle (gridDim %8==0), n-major decode.
  const int NB = gridDim.x;
  const int p = blockIdx.x;
  const int l = (p & 7) * (NB >> 3) + (p >> 3);
  const int pb = nbm * nbn;
  const int z = l / pb;
  const int mn = l - z * pb;
  const int bm = mn / nbn, bn = mn - bm * nbn;
  const unsigned short* Az = A + (long)z * sA;
  const unsigned short* Bz = B + (long)z * sB;
  const long brow = (long)bm * BM, bcol = (long)bn * BN;

  // PV: build inv[BM] from rs before the K-loop (region smem+STG).
  float* invp = (float*)(smem + STG);
  if constexpr (MODE == M_PV) {
    if (tid < BM) {
      const float* r8 = rs + ((long)z * 2048 + brow + tid) * 8;
      float s = ((r8[0] + r8[1]) + (r8[2] + r8[3])) +
                ((r8[4] + r8[5]) + (r8[6] + r8[7]));
      invp[tid] = 1.0f / s;
    }
  }

  // staging: each load = 512 thr x 16B = 64 rows x 128B. source col is
  // pre-swizzled so linear LDS write == swizzled layout (m173/m201 pattern).
  const int srow = tid >> 3;  // 0..63
  const int scolb = ((tid & 7) * 16) ^ ((srow & 7) << 4);

  auto stageA = [&](int buf, int half, int kt) {
#pragma unroll
    for (int part = 0; part < LA; ++part) {
      const char* g = (const char*)Az +
          ((brow + half * (BM / 2) + part * 64 + srow) * (long)LDA + kt) * 2 +
          scolb;
      __builtin_amdgcn_global_load_lds(
          GL_G(g),
          GL_L(smem + (buf * 2 + half) * AHALF + part * 8192 + wid * 1024),
          16, 0, 0);
    }
  };
  auto stageB = [&](int buf, int half, int kt) {
#pragma unroll
    for (int part = 0; part < LB; ++part) {
      const char* g = (const char*)Bz +
          ((bcol + half * (BN / 2) + part * 64 + srow) * (long)LDB + kt) * 2 +
          scolb;
      __builtin_amdgcn_global_load_lds(
          GL_G(g),
          GL_L(smem + 4 * AHALF + (buf * 2 + half) * BHALF + part * 8192 +
               wid * 1024),
          16, 0, 0);
    }
  };

  f32x4 acc[2 * AF][NREP];
#pragma unroll
  for (int m = 0; m < 2 * AF; ++m)
#pragma unroll
    for (int n = 0; n < NREP; ++n) acc[m][n] = (f32x4){0.f, 0.f, 0.f, 0.f};

  short8 af[AF][2];   // current A-half (reloaded each phase)
  short8 b0[NPH][2];  // B-half 0 (read PH0, reused PH1)
  short8 b1[NPH][2];  // B-half 1 (read PH0, reused PH1)

  // per-lane invariant pieces of the ds_read addresses
  const int aRow = wm * (BM / 4) + fr;          // + i*16
  const int bRow = wn * (WVN / 2) + fr;         // + j*16
  const int swz = (fr & 7) << 4;

  auto readA = [&](auto curC, int mh) {
    constexpr int cur = decltype(curC)::value;
#pragma unroll
    for (int i = 0; i < AF; ++i)
#pragma unroll
      for (int ks = 0; ks < 2; ++ks) {
        const int off = (cur * 2 + mh) * AHALF + (aRow + i * 16) * 128 +
                        ((ks * 64 + kq * 16) ^ swz);
        af[i][ks] = *(const short8*)(smem + off);
      }
  };
  auto readB = [&](short8 (&bf_)[NPH][2], auto curC, int nh) {
    constexpr int cur = decltype(curC)::value;
#pragma unroll
    for (int j = 0; j < NPH; ++j)
#pragma unroll
      for (int ks = 0; ks < 2; ++ks) {
        const int off = 4 * AHALF + (cur * 2 + nh) * BHALF +
                        (bRow + j * 16) * 128 + ((ks * 64 + kq * 16) ^ swz);
        bf_[j][ks] = *(const short8*)(smem + off);
      }
  };
  auto mfma2 = [&](int mh) {  // A-half mh x {B0, B1}
    __builtin_amdgcn_s_setprio(1);
#pragma unroll
    for (int i = 0; i < AF; ++i)
#pragma unroll
      for (int nh = 0; nh < 2; ++nh)
#pragma unroll
        for (int j = 0; j < NPH; ++j)
#pragma unroll
          for (int ks = 0; ks < 2; ++ks) {
            short8(&bb)[NPH][2] = nh ? b1 : b0;
            acc[mh * AF + i][nh * NPH + j] =
                __builtin_amdgcn_mfma_f32_16x16x32_bf16(
                    af[i][ks], bb[j][ks], acc[mh * AF + i][nh * NPH + j], 0, 0,
                    0);
          }
    __builtin_amdgcn_s_setprio(0);
  };

  // one K-tile body; CUR compile-time.
  auto tile = [&](auto curC, int t) {
    constexpr int cur = decltype(curC)::value;
    constexpr int nxt = cur ^ 1;
    const int kt1 = (t + 1) * BK;
    const int kt2 = (t + 2) * BK;
    const bool more2 = (t + 2) < NT;

    // ---- PH0: read A0,B0,B1; stage A1(t+1)[t>=1]; MFMA A0x{B0,B1} ----
    readA(std::integral_constant<int, cur>{}, 0);
    readB(b0, std::integral_constant<int, cur>{}, 0);
    readB(b1, std::integral_constant<int, cur>{}, 1);
    if (t >= 1 && t + 1 < NT) stageA(nxt, 1, kt1);
    mfma2(0);
    barrier_();

    // ---- PH1: read A1; stage A0,B0,B1(t+2); MFMA A1x{B0,B1}; wait ----
    readA(std::integral_constant<int, cur>{}, 1);
    if (more2) { stageA(cur, 0, kt2); stageB(cur, 0, kt2); stageB(cur, 1, kt2); }
    mfma2(1);
    if (more2) waitv<WAITN>(); else waitv<0>();
    barrier_();
  };

  // prologue: tiles 0 and 1 fully staged; drain tile 0 only.
  stageA(0, 0, 0); stageB(0, 0, 0); stageB(0, 1, 0); stageA(0, 1, 0);
  stageA(1, 0, BK); stageB(1, 0, BK); stageB(1, 1, BK); stageA(1, 1, BK);
  waitv<TL>();
  barrier_();

#pragma unroll 1
  for (int tt = 0; tt < NT; tt += 2) {
    tile(std::integral_constant<int, 0>{}, tt);
    tile(std::integral_constant<int, 1>{}, tt + 1);
  }

  // ---- epilogue: C/D layout col = lane&15, row = (lane>>4)*4 + r ----
  float rp[2 * AF][4];
  if constexpr (MODE == M_SCORES) {
#pragma unroll
    for (int m = 0; m < 2 * AF; ++m)
#pragma unroll
      for (int r = 0; r < 4; ++r) rp[m][r] = 0.f;
  }

#pragma unroll
  for (int m = 0; m < 2 * AF; ++m) {
    const int mh = m / AF, i = m % AF;
    const long rowg0 = brow + mh * (BM / 2) + wm * (BM / 4) + i * 16 + kq * 4;
    const int lrow0 = mh * (BM / 2) + wm * (BM / 4) + i * 16 + kq * 4;
#pragma unroll
    for (int n = 0; n < NREP; ++n) {
      const int nh = n / NPH, j = n % NPH;
      const long colg = bcol + nh * (BN / 2) + wn * (WVN / 2) + j * 16 + fr;
      f32x4 v = acc[m][n];
      if constexpr (MODE == M_SCORES) {
        unsigned short* Cz = (unsigned short*)C + z * sC;
#pragma unroll
        for (int r = 0; r < 4; ++r) {
          float e = __expf(v[r] * scale);
          Cz[(rowg0 + r) * LDC + colg] = f2bf(e);
          rp[m][r] += e;
        }
      } else if constexpr (MODE == M_PV) {
        float* Cz = (float*)C + z * sC;
#pragma unroll
        for (int r = 0; r < 4; ++r)
          Cz[(rowg0 + r) * LDC + colg] = v[r] * invp[lrow0 + r];
      } else {  // M_PROJ3: fused QKV, split by column segment.
        unsigned short* Cq = (unsigned short*)C;  // Qb; Kb at +XE; Vtb at +2XE
        constexpr long XE = 4L * 2048 * 1024;
        if (colg < 2048) {
          unsigned short* dst = Cq + (colg >> 10) * XE;
#pragma unroll
          for (int r = 0; r < 4; ++r)
            dst[(rowg0 + r) * 1024 + (colg & 1023)] = f2bf(v[r]);
        } else {
          // transposed store: Vt[b][e][s], b = row>>11, s = row&2047
          const long e = colg - 2048;
          const long bb = rowg0 >> 11;
          ushort4 pk;
          pk.x = f2bf(v[0]); pk.y = f2bf(v[1]);
          pk.z = f2bf(v[2]); pk.w = f2bf(v[3]);
          *(ushort4*)(Cq + 2 * XE + bb * (1024L * 2048) + e * 2048 +
                      (rowg0 & 2047)) = pk;
        }
      }
    }
  }

  if constexpr (MODE == M_SCORES) {
    // reduce rp over fr lanes, across the 4 wn waves via LDS, one store/row.
#pragma unroll
    for (int m = 0; m < 2 * AF; ++m)
#pragma unroll
      for (int r = 0; r < 4; ++r) {
        float tv = rp[m][r];
        tv += __shfl_xor(tv, 1);
        tv += __shfl_xor(tv, 2);
        tv += __shfl_xor(tv, 4);
        tv += __shfl_xor(tv, 8);
        rp[m][r] = tv;
      }
    float* part = (float*)smem;  // [BM][4] — staging region is dead now
    if (fr == 0) {
#pragma unroll
      for (int m = 0; m < 2 * AF; ++m) {
        const int mh = m / AF, i = m % AF;
#pragma unroll
        for (int r = 0; r < 4; ++r) {
          const int lrow = mh * (BM / 2) + wm * (BM / 4) + i * 16 + kq * 4 + r;
          part[lrow * 4 + wn] = rp[m][r];
        }
      }
    }
    __syncthreads();
    if (tid < BM) {
      float s = (part[tid * 4 + 0] + part[tid * 4 + 1]) +
                (part[tid * 4 + 2] + part[tid * 4 + 3]);
      rs[((long)z * 2048 + brow + tid) * 8 + bn] = s;
    }
  }
}

// named kernel wrappers
__global__ __launch_bounds__(512, 4) void gemm_proj(
    const unsigned short* __restrict__ A, const unsigned short* __restrict__ B,
    unsigned short* __restrict__ C, long sA, long sB, long sC, float scale,
    int nbm, int nbn) {
  __shared__ __align__(16) char smem[65536];
  gemm_body<128, 128, M_PROJ3, 1024, 1024, 1024, 1024, unsigned short>(
      A, B, C, sA, sB, sC, scale, nbm, nbn, smem, nullptr);
}
__global__ __launch_bounds__(512, 2) void gemm_scores(
    const unsigned short* __restrict__ A, const unsigned short* __restrict__ B,
    unsigned short* __restrict__ C, long sA, long sB, long sC, float scale,
    int nbm, int nbn, float* rs) {
  __shared__ __align__(16) char smem[131072];
  gemm_body<256, 256, M_SCORES, 1024, 1024, 1024, 2048, unsigned short>(
      A, B, C, sA, sB, sC, scale, nbm, nbn, smem, rs);
}
__global__ __launch_bounds__(512, 4) void gemm_pv(
    const unsigned short* __restrict__ A, const unsigned short* __restrict__ B,
    float* __restrict__ C, long sA, long sB, long sC, float scale,
    int nbm, int nbn, float* rs) {
  __shared__ __align__(16) char smem[65536 + 512];
  gemm_body<128, 128, M_PV, 2048, 2048, 2048, 1024, float>(
      A, B, C, sA, sB, sC, scale, nbm, nbn, smem, rs);
}

// ---------------------------------------------------------------------------
extern "C" void kernel_launch(void* const* d_in, const int* in_sizes, int n_in,
                              void* d_out, int out_size, void* d_ws,
                              size_t ws_size, hipStream_t stream) {
  const float* x = (const float*)d_in[0];
  const float* Wq = (const float*)d_in[1];
  const float* Wk = (const float*)d_in[2];
  const float* Wv = (const float*)d_in[3];
  float* out = (float*)d_out;

  const long XE = 4L * 2048 * 1024;  // 8,388,608 elems
  const long WE = 1024L * 1024;      // 1,048,576 elems
  const long SE = 4L * 2048 * 2048;  // 16,777,216 elems

  unsigned short* xb = (unsigned short*)d_ws;
  unsigned short* Wqb = xb + XE;     // Wq,Wk,Wv contiguous = Wcat[3072][1024]
  unsigned short* Qb = Wqb + 3 * WE; // Qb,Kb,Vtb contiguous
  unsigned short* Kb = Qb + XE;
  unsigned short* Vtb = Qb + 2 * XE; // [b][e][s] (transposed V)
  unsigned short* Sb = Vtb + XE;     // [b][q][k] p~ = exp(s/32), bf16
  float* rs = (float*)(Sb + SE);     // [4*2048 rows][8 colblocks] partials
  if (ws_size < (size_t)(4 * XE + 3 * WE + SE) * 2 + 8192 * 8 * 4) return;

  // fused casts: (XE + 3*WE)/8 threads = 1,441,792 -> 5632 blocks exact
  cast_all<<<5632, 256, 0, stream>>>(x, Wq, Wk, Wv, xb, Wqb);

  // fused QKV projection: [8192 x 3072] = x @ Wcat^T, BM=BN=128,
  // nbm=64 x nbn=24 = 1536 blocks = 3 full rounds at 2 blocks/CU.
  gemm_proj<<<1536, 512, 0, stream>>>(xb, Wqb, Qb, 0, 0, 0, 1.0f, 64, 24);
  // p~[b][q][k] = exp(Qb Kb^T / 32), per batch + row partial sums.
  gemm_scores<<<256, 512, 0, stream>>>(Qb, Kb, Sb, 2048L * 1024, 2048L * 1024,
                                       2048L * 2048, 0.03125f, 8, 8, rs);
  // out[b][q][e] = (p~ Vt^T) / rowsum: BM=BN=128 -> 16*8*4 = 512 blocks,
  // 1 full round at 2 blocks/CU.
  gemm_pv<<<512, 512, 0, stream>>>(Sb, Vtb, out, 2048L * 2048, 1024L * 2048,
                                   2048L * 1024, 1.0f, 16, 8, rs);
}

// Round 15
// 136.485 us; speedup vs baseline: 1.0473x; 1.0104x over previous
//
#include <hip/hip_runtime.h>
#include <hip/hip_bf16.h>
#include <stdint.h>
#include <type_traits>

// ---------------------------------------------------------------------------
// Fused attention: out = softmax((x Wq^T)(x Wk^T)^T / sqrt(d)) (x Wv^T)
// B=4, S=2048, D=1024, fp32 in/out, bf16 MFMA internal compute.
//
// R15: shape-driven decomposition. Every GEMM dispatch = exact multiple of
// resident capacity, in its best-known engine geometry:
//   QK-proj : [8192x2048] = x @ [Wq;Wk]^T, 256x256, 32x8 = 256 blocks (1 rnd)
//   V-proj  : [8192x1024] = x @ Wv^T (transposed store), 128x256,
//             64x4 = 256 blocks (1 rnd)
//   scores  : exp(Q K^T/32) + rowsums, 256x256, 8x8x4 = 256 blocks (1 rnd)
//   PV      : (p~ Vt^T)/rowsum, 128x128 @ 2 blocks/CU, 512 blocks (1 rnd)
// Engine: 2-phase K-tile, counted vmcnt, T2 swizzle (unchanged from R12-R14).
// ---------------------------------------------------------------------------

typedef __attribute__((ext_vector_type(8))) short short8;
typedef __attribute__((ext_vector_type(4))) float f32x4;

#define GL_G(p) ((const __attribute__((address_space(1))) void*)(p))
#define GL_L(p) ((__attribute__((address_space(3))) void*)(p))

__device__ __forceinline__ float bf2f(unsigned short u) {
  union { float f; uint32_t i; } c; c.i = ((uint32_t)u) << 16; return c.f;
}
__device__ __forceinline__ unsigned short f2bf(float f) {
  __hip_bfloat16 h = __float2bfloat16(f);
  return *reinterpret_cast<unsigned short*>(&h);
}

// ---- fused cast: x (XE elems) then Wq,Wk,Wv (WE each) -> bf16, exact grid --
__global__ __launch_bounds__(256) void cast_all(
    const float* __restrict__ x, const float* __restrict__ wq,
    const float* __restrict__ wk, const float* __restrict__ wv,
    unsigned short* __restrict__ xb, unsigned short* __restrict__ wb) {
  const long XE = 4L * 2048 * 1024;
  const long WE = 1L << 20;
  long j = ((long)blockIdx.x * blockDim.x + threadIdx.x) * 8;
  const float* src;
  unsigned short* dst;
  long loc;
  if (j < XE) {
    src = x; dst = xb; loc = j;
  } else {
    long jw = j - XE;
    int sel = (int)(jw >> 20);
    src = (sel == 0) ? wq : (sel == 1) ? wk : wv;
    dst = wb + (long)sel * WE;
    loc = jw & (WE - 1);
  }
  float4 a = *(const float4*)(src + loc);
  float4 b = *(const float4*)(src + loc + 4);
  uint4 pk;
  pk.x = (uint32_t)f2bf(a.x) | ((uint32_t)f2bf(a.y) << 16);
  pk.y = (uint32_t)f2bf(a.z) | ((uint32_t)f2bf(a.w) << 16);
  pk.z = (uint32_t)f2bf(b.x) | ((uint32_t)f2bf(b.y) << 16);
  pk.w = (uint32_t)f2bf(b.z) | ((uint32_t)f2bf(b.w) << 16);
  *(uint4*)(dst + ((j < XE) ? j : loc)) = pk;
}

template <int N>
__device__ __forceinline__ void waitv() {
  asm volatile("s_waitcnt vmcnt(%0)" :: "n"(N) : "memory");
}
__device__ __forceinline__ void barrier_() {
  asm volatile("" ::: "memory");
  __builtin_amdgcn_s_barrier();
  asm volatile("" ::: "memory");
}

// modes
#define M_PROJQK 0
#define M_SCORES 1
#define M_PV 2
#define M_PROJV 3

// ---------------- NT GEMM device body, BMxBN tile, BK=64, 2-phase ---------
// C[m,n] = scale-op( sum_k A[m,k] B[n,k] ). All shape params compile-time.
// Grid 1D = nbm*nbn*nz, %8==0. 8 waves (2M x 4N); wave tile (BM/2)x(BN/4).
// M_PROJQK: OUT bf16 split by col segment: cols<1024 -> C, else C+XE.
// M_PROJV : OUT bf16 transposed per batch: Vt[b][e][s], b=row>>11.
// M_SCORES: OUT bf16 = exp(v*scale); rowsum partials -> rs[grow*8 + bn].
// M_PV    : OUT f32 = v * inv(rowsum from rs).
template <int BM, int BN, int MODE, int K, int LDA, int LDB, int LDC,
          typename OUT_T>
__device__ __forceinline__ void gemm_body(
    const unsigned short* __restrict__ A, const unsigned short* __restrict__ B,
    OUT_T* __restrict__ C, long sA, long sB, long sC, float scale, int nbm,
    int nbn, char* smem, float* __restrict__ rs) {
  constexpr int BK = 64;
  constexpr int WVN = BN / 4;    // per-wave N: 64 or 32
  constexpr int NREP = WVN / 16; // 4 or 2
  constexpr int NPH = NREP / 2;  // frags per B-half: 2 or 1
  constexpr int AF = BM / 64;    // A-frags per half per wave: 4 or 2
  constexpr int AHALF = (BM / 2) * BK * 2; // 16384 or 8192 B
  constexpr int BHALF = (BN / 2) * BK * 2; // 16384 or 8192 B
  constexpr int LA = AHALF / 8192;         // gloads per A-half
  constexpr int LB = BHALF / 8192;         // gloads per B-half
  constexpr int TL = 2 * (LA + LB);        // loads per K-tile
  constexpr int WAITN = LA + 2 * LB;       // steady vmcnt at end-PH1
  constexpr int STG = 4 * AHALF + 4 * BHALF;
  constexpr int NT = K / BK;               // K-tiles (even)
  static_assert((NT & 1) == 0 && NT >= 4, "even NT >= 4");

  const int tid = threadIdx.x;
  const int wid = tid >> 6, lane = tid & 63;
  const int wm = wid >> 2, wn = wid & 3;
  const int fr = lane & 15;
  const int kq = lane >> 4;  // 0..3

  // XCD-aware bijective swizzle (gridDim %8==0), n-major decode.
  const int NB = gridDim.x;
  const int p = blockIdx.x;
  const int l = (p & 7) * (NB >> 3) + (p >> 3);
  const int pb = nbm * nbn;
  const int z = l / pb;
  const int mn = l - z * pb;
  const int bm = mn / nbn, bn = mn - bm * nbn;
  const unsigned short* Az = A + (long)z * sA;
  const unsigned short* Bz = B + (long)z * sB;
  const long brow = (long)bm * BM, bcol = (long)bn * BN;

  // PV: build inv[BM] from rs before the K-loop (region smem+STG).
  float* invp = (float*)(smem + STG);
  if constexpr (MODE == M_PV) {
    if (tid < BM) {
      const float* r8 = rs + ((long)z * 2048 + brow + tid) * 8;
      float s = ((r8[0] + r8[1]) + (r8[2] + r8[3])) +
                ((r8[4] + r8[5]) + (r8[6] + r8[7]));
      invp[tid] = 1.0f / s;
    }
  }

  // staging: each load = 512 thr x 16B = 64 rows x 128B. source col is
  // pre-swizzled so linear LDS write == swizzled layout (m173/m201 pattern).
  const int srow = tid >> 3;  // 0..63
  const int scolb = ((tid & 7) * 16) ^ ((srow & 7) << 4);

  auto stageA = [&](int buf, int half, int kt) {
#pragma unroll
    for (int part = 0; part < LA; ++part) {
      const char* g = (const char*)Az +
          ((brow + half * (BM / 2) + part * 64 + srow) * (long)LDA + kt) * 2 +
          scolb;
      __builtin_amdgcn_global_load_lds(
          GL_G(g),
          GL_L(smem + (buf * 2 + half) * AHALF + part * 8192 + wid * 1024),
          16, 0, 0);
    }
  };
  auto stageB = [&](int buf, int half, int kt) {
#pragma unroll
    for (int part = 0; part < LB; ++part) {
      const char* g = (const char*)Bz +
          ((bcol + half * (BN / 2) + part * 64 + srow) * (long)LDB + kt) * 2 +
          scolb;
      __builtin_amdgcn_global_load_lds(
          GL_G(g),
          GL_L(smem + 4 * AHALF + (buf * 2 + half) * BHALF + part * 8192 +
               wid * 1024),
          16, 0, 0);
    }
  };

  f32x4 acc[2 * AF][NREP];
#pragma unroll
  for (int m = 0; m < 2 * AF; ++m)
#pragma unroll
    for (int n = 0; n < NREP; ++n) acc[m][n] = (f32x4){0.f, 0.f, 0.f, 0.f};

  short8 af[AF][2];   // current A-half (reloaded each phase)
  short8 b0[NPH][2];  // B-half 0 (read PH0, reused PH1)
  short8 b1[NPH][2];  // B-half 1 (read PH0, reused PH1)

  // per-lane invariant pieces of the ds_read addresses
  const int aRow = wm * (BM / 4) + fr;          // + i*16
  const int bRow = wn * (WVN / 2) + fr;         // + j*16
  const int swz = (fr & 7) << 4;

  auto readA = [&](auto curC, int mh) {
    constexpr int cur = decltype(curC)::value;
#pragma unroll
    for (int i = 0; i < AF; ++i)
#pragma unroll
      for (int ks = 0; ks < 2; ++ks) {
        const int off = (cur * 2 + mh) * AHALF + (aRow + i * 16) * 128 +
                        ((ks * 64 + kq * 16) ^ swz);
        af[i][ks] = *(const short8*)(smem + off);
      }
  };
  auto readB = [&](short8 (&bf_)[NPH][2], auto curC, int nh) {
    constexpr int cur = decltype(curC)::value;
#pragma unroll
    for (int j = 0; j < NPH; ++j)
#pragma unroll
      for (int ks = 0; ks < 2; ++ks) {
        const int off = 4 * AHALF + (cur * 2 + nh) * BHALF +
                        (bRow + j * 16) * 128 + ((ks * 64 + kq * 16) ^ swz);
        bf_[j][ks] = *(const short8*)(smem + off);
      }
  };
  auto mfma2 = [&](int mh) {  // A-half mh x {B0, B1}
    __builtin_amdgcn_s_setprio(1);
#pragma unroll
    for (int i = 0; i < AF; ++i)
#pragma unroll
      for (int nh = 0; nh < 2; ++nh)
#pragma unroll
        for (int j = 0; j < NPH; ++j)
#pragma unroll
          for (int ks = 0; ks < 2; ++ks) {
            short8(&bb)[NPH][2] = nh ? b1 : b0;
            acc[mh * AF + i][nh * NPH + j] =
                __builtin_amdgcn_mfma_f32_16x16x32_bf16(
                    af[i][ks], bb[j][ks], acc[mh * AF + i][nh * NPH + j], 0, 0,
                    0);
          }
    __builtin_amdgcn_s_setprio(0);
  };

  // one K-tile body; CUR compile-time.
  auto tile = [&](auto curC, int t) {
    constexpr int cur = decltype(curC)::value;
    constexpr int nxt = cur ^ 1;
    const int kt1 = (t + 1) * BK;
    const int kt2 = (t + 2) * BK;
    const bool more2 = (t + 2) < NT;

    // ---- PH0: read A0,B0,B1; stage A1(t+1)[t>=1]; MFMA A0x{B0,B1} ----
    readA(std::integral_constant<int, cur>{}, 0);
    readB(b0, std::integral_constant<int, cur>{}, 0);
    readB(b1, std::integral_constant<int, cur>{}, 1);
    if (t >= 1 && t + 1 < NT) stageA(nxt, 1, kt1);
    mfma2(0);
    barrier_();

    // ---- PH1: read A1; stage A0,B0,B1(t+2); MFMA A1x{B0,B1}; wait ----
    readA(std::integral_constant<int, cur>{}, 1);
    if (more2) { stageA(cur, 0, kt2); stageB(cur, 0, kt2); stageB(cur, 1, kt2); }
    mfma2(1);
    if (more2) waitv<WAITN>(); else waitv<0>();
    barrier_();
  };

  // prologue: tiles 0 and 1 fully staged; drain tile 0 only.
  stageA(0, 0, 0); stageB(0, 0, 0); stageB(0, 1, 0); stageA(0, 1, 0);
  stageA(1, 0, BK); stageB(1, 0, BK); stageB(1, 1, BK); stageA(1, 1, BK);
  waitv<TL>();
  barrier_();

#pragma unroll 1
  for (int tt = 0; tt < NT; tt += 2) {
    tile(std::integral_constant<int, 0>{}, tt);
    tile(std::integral_constant<int, 1>{}, tt + 1);
  }

  // ---- epilogue: C/D layout col = lane&15, row = (lane>>4)*4 + r ----
  float rp[2 * AF][4];
  if constexpr (MODE == M_SCORES) {
#pragma unroll
    for (int m = 0; m < 2 * AF; ++m)
#pragma unroll
      for (int r = 0; r < 4; ++r) rp[m][r] = 0.f;
  }

#pragma unroll
  for (int m = 0; m < 2 * AF; ++m) {
    const int mh = m / AF, i = m % AF;
    const long rowg0 = brow + mh * (BM / 2) + wm * (BM / 4) + i * 16 + kq * 4;
    const int lrow0 = mh * (BM / 2) + wm * (BM / 4) + i * 16 + kq * 4;
#pragma unroll
    for (int n = 0; n < NREP; ++n) {
      const int nh = n / NPH, j = n % NPH;
      const long colg = bcol + nh * (BN / 2) + wn * (WVN / 2) + j * 16 + fr;
      f32x4 v = acc[m][n];
      if constexpr (MODE == M_SCORES) {
        unsigned short* Cz = (unsigned short*)C + z * sC;
#pragma unroll
        for (int r = 0; r < 4; ++r) {
          float e = __expf(v[r] * scale);
          Cz[(rowg0 + r) * LDC + colg] = f2bf(e);
          rp[m][r] += e;
        }
      } else if constexpr (MODE == M_PV) {
        float* Cz = (float*)C + z * sC;
#pragma unroll
        for (int r = 0; r < 4; ++r)
          Cz[(rowg0 + r) * LDC + colg] = v[r] * invp[lrow0 + r];
      } else if constexpr (MODE == M_PROJQK) {
        // split by column segment: cols<1024 -> Q (C), else K (C+XE).
        constexpr long XE = 4L * 2048 * 1024;
        unsigned short* dst = (unsigned short*)C + (colg >> 10) * XE;
        const long cc = colg & 1023;
#pragma unroll
        for (int r = 0; r < 4; ++r)
          dst[(rowg0 + r) * 1024 + cc] = f2bf(v[r]);
      } else {  // M_PROJV: transposed per-batch store Vt[b][e][s]
        const long bb = rowg0 >> 11;
        ushort4 pk;
        pk.x = f2bf(v[0]); pk.y = f2bf(v[1]);
        pk.z = f2bf(v[2]); pk.w = f2bf(v[3]);
        *(ushort4*)((unsigned short*)C + bb * (1024L * 2048) + colg * 2048 +
                    (rowg0 & 2047)) = pk;
      }
    }
  }

  if constexpr (MODE == M_SCORES) {
    // reduce rp over fr lanes, across the 4 wn waves via LDS, one store/row.
#pragma unroll
    for (int m = 0; m < 2 * AF; ++m)
#pragma unroll
      for (int r = 0; r < 4; ++r) {
        float tv = rp[m][r];
        tv += __shfl_xor(tv, 1);
        tv += __shfl_xor(tv, 2);
        tv += __shfl_xor(tv, 4);
        tv += __shfl_xor(tv, 8);
        rp[m][r] = tv;
      }
    float* part = (float*)smem;  // [BM][4] — staging region is dead now
    if (fr == 0) {
#pragma unroll
      for (int m = 0; m < 2 * AF; ++m) {
        const int mh = m / AF, i = m % AF;
#pragma unroll
        for (int r = 0; r < 4; ++r) {
          const int lrow = mh * (BM / 2) + wm * (BM / 4) + i * 16 + kq * 4 + r;
          part[lrow * 4 + wn] = rp[m][r];
        }
      }
    }
    __syncthreads();
    if (tid < BM) {
      float s = (part[tid * 4 + 0] + part[tid * 4 + 1]) +
                (part[tid * 4 + 2] + part[tid * 4 + 3]);
      rs[((long)z * 2048 + brow + tid) * 8 + bn] = s;
    }
  }
}

// named kernel wrappers
__global__ __launch_bounds__(512, 2) void gemm_projqk(
    const unsigned short* __restrict__ A, const unsigned short* __restrict__ B,
    unsigned short* __restrict__ C, long sA, long sB, long sC, float scale,
    int nbm, int nbn) {
  __shared__ __align__(16) char smem[131072];
  gemm_body<256, 256, M_PROJQK, 1024, 1024, 1024, 1024, unsigned short>(
      A, B, C, sA, sB, sC, scale, nbm, nbn, smem, nullptr);
}
__global__ __launch_bounds__(512, 2) void gemm_projv(
    const unsigned short* __restrict__ A, const unsigned short* __restrict__ B,
    unsigned short* __restrict__ C, long sA, long sB, long sC, float scale,
    int nbm, int nbn) {
  __shared__ __align__(16) char smem[98304];
  gemm_body<128, 256, M_PROJV, 1024, 1024, 1024, 1024, unsigned short>(
      A, B, C, sA, sB, sC, scale, nbm, nbn, smem, nullptr);
}
__global__ __launch_bounds__(512, 2) void gemm_scores(
    const unsigned short* __restrict__ A, const unsigned short* __restrict__ B,
    unsigned short* __restrict__ C, long sA, long sB, long sC, float scale,
    int nbm, int nbn, float* rs) {
  __shared__ __align__(16) char smem[131072];
  gemm_body<256, 256, M_SCORES, 1024, 1024, 1024, 2048, unsigned short>(
      A, B, C, sA, sB, sC, scale, nbm, nbn, smem, rs);
}
__global__ __launch_bounds__(512, 4) void gemm_pv(
    const unsigned short* __restrict__ A, const unsigned short* __restrict__ B,
    float* __restrict__ C, long sA, long sB, long sC, float scale,
    int nbm, int nbn, float* rs) {
  __shared__ __align__(16) char smem[65536 + 512];
  gemm_body<128, 128, M_PV, 2048, 2048, 2048, 1024, float>(
      A, B, C, sA, sB, sC, scale, nbm, nbn, smem, rs);
}

// ---------------------------------------------------------------------------
extern "C" void kernel_launch(void* const* d_in, const int* in_sizes, int n_in,
                              void* d_out, int out_size, void* d_ws,
                              size_t ws_size, hipStream_t stream) {
  const float* x = (const float*)d_in[0];
  const float* Wq = (const float*)d_in[1];
  const float* Wk = (const float*)d_in[2];
  const float* Wv = (const float*)d_in[3];
  float* out = (float*)d_out;

  const long XE = 4L * 2048 * 1024;  // 8,388,608 elems
  const long WE = 1024L * 1024;      // 1,048,576 elems
  const long SE = 4L * 2048 * 2048;  // 16,777,216 elems

  unsigned short* xb = (unsigned short*)d_ws;
  unsigned short* Wqb = xb + XE;     // Wq,Wk,Wv contiguous = Wcat[3072][1024]
  unsigned short* Qb = Wqb + 3 * WE; // Qb,Kb,Vtb contiguous
  unsigned short* Kb = Qb + XE;
  unsigned short* Vtb = Qb + 2 * XE; // [b][e][s] (transposed V)
  unsigned short* Sb = Vtb + XE;     // [b][q][k] p~ = exp(s/32), bf16
  float* rs = (float*)(Sb + SE);     // [4*2048 rows][8 colblocks] partials
  if (ws_size < (size_t)(4 * XE + 3 * WE + SE) * 2 + 8192 * 8 * 4) return;

  // fused casts: (XE + 3*WE)/8 threads = 1,441,792 -> 5632 blocks exact
  cast_all<<<5632, 256, 0, stream>>>(x, Wq, Wk, Wv, xb, Wqb);

  // QK projection: [8192 x 2048] = x @ [Wq;Wk]^T, 256x256 tile,
  // nbm=32 x nbn=8 = 256 blocks = exactly 1 round. Split epilogue Q|K.
  gemm_projqk<<<256, 512, 0, stream>>>(xb, Wqb, Qb, 0, 0, 0, 1.0f, 32, 8);
  // V projection: [8192 x 1024] = x @ Wv^T, 128x256 tile, transposed store.
  // nbm=64 x nbn=4 = 256 blocks = exactly 1 round.
  gemm_projv<<<256, 512, 0, stream>>>(xb, Wqb + 2 * WE, Vtb, 0, 0, 0, 1.0f,
                                      64, 4);
  // p~[b][q][k] = exp(Qb Kb^T / 32), per batch + row partial sums.
  gemm_scores<<<256, 512, 0, stream>>>(Qb, Kb, Sb, 2048L * 1024, 2048L * 1024,
                                       2048L * 2048, 0.03125f, 8, 8, rs);
  // out[b][q][e] = (p~ Vt^T) / rowsum: BM=BN=128 -> 16*8*4 = 512 blocks,
  // 1 full round at 2 blocks/CU.
  gemm_pv<<<512, 512, 0, stream>>>(Sb, Vtb, out, 2048L * 2048, 1024L * 2048,
                                   2048L * 1024, 1.0f, 16, 8, rs);
}